// Round 1
// 251.360 us; speedup vs baseline: 1.0320x; 1.0320x over previous
//
#include <hip/hip_runtime.h>
#include <math.h>

// LSTM B=1024,T=512,IN=16,H=64,OUT=8, gates i,f,g,o.
// R13: CHAIN-SHORTENING on R12 (259us, ~1140cyc/step). Wall = 512 x serial
// chain; co-resident blocks already overlap, so only chain latency counts.
//   1) lane^8 exchange: ds_swizzle (LDS pipe, ~100+cyc, inside lgkm drain)
//      -> v_mov_b32_dpp row_ror:8 (VALU, ~4cyc). LDS ops/step 5 -> 3.
//   2) activation scales folded into fp16 weights+bias: rows i,f,o x(-L2E),
//      g x(+L2E2); cell kept pre-scaled cs = L2E2*c. Removes 2 serial
//      v_mul before the exp2s.
//   3) unconditional ds_write: half1 dumps to +64 slot in widened row
//      (HSTRIDE 136) -> no exec-mask toggle on the chain tail.
//   4) s_setprio(1) around the serial act->write tail.
// Else identical to R12: BT=2, 512 blocks (2/CU), wave w owns j-slice
// [16w,16w+16), tiles tt = gate type, fp16 weights pinned, h via dbuf LDS,
// 1 lite barrier/step, x 2 steps ahead, gate-pairing across lane^8.

#define LSTM_T 512
#define LSTM_IN 16
#define LSTM_H 64
#define LSTM_OUT 8
#define BT 2
#define HSTRIDE 136        // halves per batch row: 64 h + 64 half1-dump + 8 pad

#define L2E   1.44269504088896340736f
#define L2E2  2.88539008177792681472f

typedef _Float16 half8  __attribute__((ext_vector_type(8)));
typedef float    floatx4 __attribute__((ext_vector_type(4)));

static __device__ __forceinline__ float fast_rcp(float x) { return __builtin_amdgcn_rcpf(x); }
static __device__ __forceinline__ float fast_exp2(float x) { return __builtin_amdgcn_exp2f(x); }
// p pre-scaled by log2e:
static __device__ __forceinline__ float sigm2(float p) { return fast_rcp(1.0f + fast_exp2(-p)); }
static __device__ __forceinline__ void pin4(int4& v) {
    asm volatile("" : "+v"(v.x), "+v"(v.y), "+v"(v.z), "+v"(v.w));
}
static __device__ __forceinline__ void pinf4(float4& v) {
    asm volatile("" : "+v"(v.x), "+v"(v.y), "+v"(v.z), "+v"(v.w));
}
static __device__ __forceinline__ void lite_barrier() {
    asm volatile("s_waitcnt lgkmcnt(0)\n\ts_barrier" ::: "memory");
}
static __device__ __forceinline__ unsigned pk2h(float a, float b) {
    return __builtin_bit_cast(unsigned, __builtin_amdgcn_cvt_pkrtz(a, b));
}
static __device__ __forceinline__ half8 to_h8(float4 a, float4 b) {
    uint4 u = make_uint4(pk2h(a.x, a.y), pk2h(a.z, a.w), pk2h(b.x, b.y), pk2h(b.z, b.w));
    return __builtin_bit_cast(half8, u);
}
static __device__ __forceinline__ int4 cvt8h(float4 a, float4 b) {
    return __builtin_bit_cast(int4, to_h8(a, b));
}
static __device__ __forceinline__ float4 ld4(const float* p) {
    return *reinterpret_cast<const float4*>(p);
}
static __device__ __forceinline__ float4 scl4(float4 v, float s) {
    return make_float4(s * v.x, s * v.y, s * v.z, s * v.w);
}
static __device__ __forceinline__ float sel4(floatx4 v, bool r0, bool r1) {
    float lo = r0 ? v[1] : v[0];
    float hi = r0 ? v[3] : v[2];
    return r1 ? hi : lo;
}
// exchange with lane^8 via DPP: row_ror:8 on a 16-lane row maps m -> m^8
// (full-rate VALU, no LDS pipe, no lgkmcnt involvement).
static __device__ __forceinline__ float dpp8(float v) {
    int r = __builtin_amdgcn_update_dpp(0, __builtin_bit_cast(int, v),
                                        0x128, 0xF, 0xF, false);
    return __builtin_bit_cast(float, r);
}

__global__ __launch_bounds__(256, 2)
void lstm_mfma_kernel(const float* __restrict__ x,
                      const float* __restrict__ W_ih,
                      const float* __restrict__ W_hh,
                      const float* __restrict__ b_ih,
                      const float* __restrict__ b_hh,
                      const float* __restrict__ W_fc,
                      const float* __restrict__ b_fc,
                      float* __restrict__ out) {
    const int tid   = threadIdx.x;
    const int lane  = tid & 63;
    const int w     = tid >> 6;        // wave -> j-slice [16w, 16w+16)
    const int q     = lane >> 4;       // k-quad / C row group
    const int m     = lane & 15;       // A row-in-tile / B col / C col
    const int b     = m & 1;           // real batch (cols = 2 b x 8 replicas)
    const int rho   = (m >> 1) & 3;    // replica id -> C row r to activate
    const bool r0   = (rho & 1) != 0;
    const bool r1   = (rho & 2) != 0;
    const bool h1   = (m & 8) != 0;    // gate-pair half: 0 = f/i, 1 = g/o
    const int jmine = 16 * w + 4 * q + rho;   // this lane's hidden index
    const bool wr   = (m < 8);         // half0 holds the valid c/h state
    const int woff  = b * HSTRIDE + jmine + (h1 ? 64 : 0);  // half1 -> dump
    const int bbase = blockIdx.x * BT;

    // activation act(u) = a1 + b1 * rcp(1 + exp2(u)), scale baked in weights:
    //   half0 (sigma): w-rows x(-L2E), a=0, b=+1
    //   half1 eval1 (tanh): g-rows x(+L2E2), a=1, b=-2
    const float a1 = h1 ? 1.0f : 0.0f;
    const float b1 = h1 ? -2.0f : 1.0f;

    __shared__ __align__(16) _Float16 hbuf[2][BT][HSTRIDE]; // h state, dbuf
    __shared__ __align__(16) float hfin[BT][LSTM_H];        // final h for FC

    // ---- weights as pinned fp16 A-fragments, PRE-SCALED per gate ----
    // tile tt = gate type (0=i,1=f,2=g,3=o); A row = tt*64 + 16w + m.
    int4 Ah[4][2], Ax[4];
    float4 bias4[4];
    #pragma unroll
    for (int tt = 0; tt < 4; ++tt) {
        const float sc = (tt == 2) ? L2E2 : -L2E;
        const int gt = tt * 64 + 16 * w + m;
        #pragma unroll
        for (int c = 0; c < 2; ++c) {
            const float* s = W_hh + gt * LSTM_H + 32 * c + 8 * q;
            Ah[tt][c] = cvt8h(scl4(ld4(s), sc), scl4(ld4(s + 4), sc));
            pin4(Ah[tt][c]);
        }
        float4 xa = make_float4(0.f, 0.f, 0.f, 0.f), xb = xa;
        if (q < 2) {
            const float* s = W_ih + gt * LSTM_IN + 8 * q;
            xa = ld4(s); xb = ld4(s + 4);
        }
        Ax[tt] = cvt8h(scl4(xa, sc), scl4(xb, sc));
        pin4(Ax[tt]);
        const int gb = tt * 64 + 16 * w + 4 * q;
        float4 bi = ld4(b_ih + gb), bh = ld4(b_hh + gb);
        bias4[tt] = make_float4(sc * (bi.x + bh.x), sc * (bi.y + bh.y),
                                sc * (bi.z + bh.z), sc * (bi.w + bh.w));
        pinf4(bias4[tt]);
    }

    // ---- zero hbuf[0] h-region (h_{-1} = 0): 2 batches * 64 halves ----
    if (tid < 64) {
        int bb = tid >> 5, jj = tid & 31;
        reinterpret_cast<int*>(&hbuf[0][bb][0])[jj] = 0;
    }

    // ---- x: lane covers batch b, elements 8q..8q+7 (q<2 real) ----
    const float* xp = x + (size_t)(bbase + b) * LSTM_T * LSTM_IN + 8 * q;
    float4 xA0 = make_float4(0.f, 0.f, 0.f, 0.f), xA1 = xA0;  // even steps
    float4 xB0 = xA0, xB1 = xA0;                              // odd steps
    if (q < 2) {
        xA0 = ld4(xp);              xA1 = ld4(xp + 4);               // x_0
        xB0 = ld4(xp + LSTM_IN);    xB1 = ld4(xp + LSTM_IN + 4);     // x_1
    }
    __syncthreads();   // hbuf zeros visible

    float cs = 0.0f, hreg = 0.0f;   // cs = L2E2 * c (pre-scaled cell)

#define STEP(T_, X0, X1)                                                        \
    {                                                                           \
        const _Float16* cur = &hbuf[(T_) & 1][0][0];                            \
        _Float16*       nxt = &hbuf[((T_) + 1) & 1][0][0];                      \
        /* h_{t-1} B-frags (col m -> batch b): issue first, fill with x-MFMA */ \
        half8 bh0 = *reinterpret_cast<const half8*>(cur + b * HSTRIDE + 8 * q); \
        half8 bh1 = *reinterpret_cast<const half8*>(cur + b * HSTRIDE + 32 + 8 * q); \
        half8 xf = to_h8(X0, X1);                                               \
        floatx4 acc[4];                                                         \
        _Pragma("unroll")                                                       \
        for (int tt = 0; tt < 4; ++tt)                                          \
            acc[tt] = __builtin_amdgcn_mfma_f32_16x16x32_f16(                   \
                __builtin_bit_cast(half8, Ax[tt]), xf,                          \
                __builtin_bit_cast(floatx4, bias4[tt]), 0, 0, 0);               \
        /* reload this reg set with x_{t+2} (2 steps of slack) */               \
        if (q < 2 && (T_) + 2 < LSTM_T) {                                       \
            X0 = ld4(xp + (size_t)((T_) + 2) * LSTM_IN);                        \
            X1 = ld4(xp + (size_t)((T_) + 2) * LSTM_IN + 4);                    \
        }                                                                       \
        _Pragma("unroll")                                                       \
        for (int tt = 0; tt < 4; ++tt)                                          \
            acc[tt] = __builtin_amdgcn_mfma_f32_16x16x32_f16(                   \
                __builtin_bit_cast(half8, Ah[tt][0]), bh0, acc[tt], 0, 0, 0);   \
        _Pragma("unroll")                                                       \
        for (int tt = 0; tt < 4; ++tt)                                          \
            acc[tt] = __builtin_amdgcn_mfma_f32_16x16x32_f16(                   \
                __builtin_bit_cast(half8, Ah[tt][1]), bh1, acc[tt], 0, 0, 0);   \
        __builtin_amdgcn_s_setprio(1);                                          \
        /* gate-paired preacts: eval1 = f|g, eval2 = i|o (half0|half1) */       \
        floatx4 v1, v2;                                                         \
        _Pragma("unroll")                                                       \
        for (int r = 0; r < 4; ++r) {                                           \
            v1[r] = h1 ? acc[2][r] : acc[1][r];                                 \
            v2[r] = h1 ? acc[3][r] : acc[0][r];                                 \
        }                                                                       \
        float u1 = sel4(v1, r0, r1);                                            \
        float u2 = sel4(v2, r0, r1);                                            \
        /* scales pre-folded: act = a1 + b1*rcp(1+exp2(u)) directly */          \
        float act1 = fmaf(b1, fast_rcp(1.0f + fast_exp2(u1)), a1);              \
        float act2 = fast_rcp(1.0f + fast_exp2(u2));  /* sigma always */        \
        float act2K = act2 * L2E2;     /* off-chain, during DPP */              \
        /* swap with partner lane^8 via DPP: half0 gets tanh(g), sigma(o) */    \
        float g_in = dpp8(act1);                                                \
        float o_in = dpp8(act2);                                                \
        /* pre-scaled cell: cs = f*cs + (L2E2*i)*g ; tanh(c)=1-2/(1+exp2(cs)) */\
        cs = fmaf(act1, cs, act2K * g_in);                                      \
        float th = fmaf(-2.0f, fast_rcp(1.0f + fast_exp2(cs)), 1.0f);           \
        hreg = o_in * th;                                                       \
        /* unconditional write: half1 lands in dump slots [64,128) */           \
        nxt[woff] = (_Float16)hreg;                                             \
        __builtin_amdgcn_s_setprio(0);                                          \
        lite_barrier();                                                         \
    }

    for (int t = 0; t < LSTM_T; t += 2) {
        STEP(t,     xA0, xA1)
        STEP(t + 1, xB0, xB1)
    }
#undef STEP

    // ---- final h (fp32) -> LDS, then FC + sigmoid ----
    if (wr) hfin[b][jmine] = hreg;
    __syncthreads();

    if (tid < BT * LSTM_OUT) {
        int bb = tid >> 3, o = tid & 7;
        float s = b_fc[o];
        #pragma unroll
        for (int j4 = 0; j4 < LSTM_H / 4; ++j4) {
            float4 wv = ld4(W_fc + o * LSTM_H + 4 * j4);
            float4 hv = *reinterpret_cast<const float4*>(&hfin[bb][4 * j4]);
            s = fmaf(wv.x, hv.x, s);
            s = fmaf(wv.y, hv.y, s);
            s = fmaf(wv.z, hv.z, s);
            s = fmaf(wv.w, hv.w, s);
        }
        out[(size_t)(bbase + bb) * LSTM_OUT + o] = sigm2(s * L2E);
    }
}

extern "C" void kernel_launch(void* const* d_in, const int* in_sizes, int n_in,
                              void* d_out, int out_size, void* d_ws, size_t ws_size,
                              hipStream_t stream) {
    const float* x    = (const float*)d_in[0];
    const float* W_ih = (const float*)d_in[1];
    const float* W_hh = (const float*)d_in[2];
    const float* b_ih = (const float*)d_in[3];
    const float* b_hh = (const float*)d_in[4];
    const float* W_fc = (const float*)d_in[5];
    const float* b_fc = (const float*)d_in[6];
    float* out = (float*)d_out;

    lstm_mfma_kernel<<<1024 / BT, 256, 0, stream>>>(
        x, W_ih, W_hh, b_ih, b_hh, W_fc, b_fc, out);
}